// Round 1
// baseline (547.604 us; speedup 1.0000x reference)
//
#include <hip/hip_runtime.h>
#include <math.h>

constexpr int kNumLevels = 16;
constexpr int kTableSize = 1 << 19;   // 524288
constexpr int kNRays     = 16384;

// out layout (floats): rgb[16384*3] | depth[16384] | acc[16384] | weights[16384*64]
constexpr int kOffDepth   = kNRays * 3;          // 49152
constexpr int kOffAcc     = kOffDepth + kNRays;  // 65536
constexpr int kOffWeights = kOffAcc + kNRays;    // 81920

template<int FIN, int FOUT, bool RELU>
__device__ __forceinline__ void dense_layer(const float* in,
                                            const float* __restrict__ W,
                                            const float* __restrict__ b,
                                            float* out) {
#pragma unroll
    for (int j = 0; j < FOUT; ++j) out[j] = b[j];
#pragma unroll
    for (int i = 0; i < FIN; ++i) {
        const float a = in[i];
#pragma unroll
        for (int j = 0; j < FOUT; ++j) out[j] = fmaf(a, W[i * FOUT + j], out[j]);
    }
    if constexpr (RELU) {
#pragma unroll
        for (int j = 0; j < FOUT; ++j) out[j] = fmaxf(out[j], 0.0f);
    }
}

__device__ __forceinline__ float wave_sum(float v) {
#pragma unroll
    for (int off = 32; off > 0; off >>= 1) v += __shfl_xor(v, off, 64);
    return v;
}

__global__ __launch_bounds__(256) void nerf_fused_kernel(
    const float* __restrict__ rays_o, const float* __restrict__ rays_d,
    const float* __restrict__ tables,
    const float* __restrict__ Wg0, const float* __restrict__ bg0,
    const float* __restrict__ Wg1, const float* __restrict__ bg1,
    const float* __restrict__ Wd,  const float* __restrict__ bd,
    const float* __restrict__ Wc0, const float* __restrict__ bc0,
    const float* __restrict__ Wc1, const float* __restrict__ bc1,
    const float* __restrict__ Wc2, const float* __restrict__ bc2,
    const float* __restrict__ Wch, const float* __restrict__ bch,
    float* __restrict__ out)
{
    const int ray  = blockIdx.x * 4 + (threadIdx.x >> 6);
    const int lane = threadIdx.x & 63;
    if (ray >= kNRays) return;

    const float ox = rays_o[ray * 3 + 0];
    const float oy = rays_o[ray * 3 + 1];
    const float oz = rays_o[ray * 3 + 2];
    const float dx = rays_d[ray * 3 + 0];
    const float dy = rays_d[ray * 3 + 1];
    const float dz = rays_d[ray * 3 + 2];

    // z_vals: linspace(0,1,64) computed as i * (1/63) in f32 (JAX style), z = near + (far-near)*t
    const float step = 1.0f / 63.0f;
    const float t0 = (float)lane * step;
    const float z  = 0.1f + 1.4f * t0;
    const float t1 = (float)(lane + 1) * step;
    const float zn = 0.1f + 1.4f * t1;          // next sample's z (for dists)

    const float px = ox + dx * z;
    const float py = oy + dy * z;
    const float pz = oz + dz * z;

    // ---- hash encode: 16 levels, 2 feats each ----
    float feats[32];
#pragma unroll
    for (int l = 0; l < kNumLevels; ++l) {
        const float res = (float)(32 << l);
        const float rm1 = res - 1.0f;
        float sx = (px + 1.0f) * 0.5f * rm1; sx = fminf(fmaxf(sx, 0.0f), rm1);
        float sy = (py + 1.0f) * 0.5f * rm1; sy = fminf(fmaxf(sy, 0.0f), rm1);
        float sz = (pz + 1.0f) * 0.5f * rm1; sz = fminf(fmaxf(sz, 0.0f), rm1);
        const float idxf = sx * res * res + sy * res + sz;
        const float size_m1 = (l == 0) ? 32767.0f : (l == 1) ? 262143.0f : 524287.0f;
        const int idx = (int)fminf(idxf, size_m1);   // trunc toward zero, matches astype(int32)
        const float2 f2 = *reinterpret_cast<const float2*>(
            tables + ((size_t)l * kTableSize + (size_t)idx) * 2);
        feats[2 * l]     = f2.x;
        feats[2 * l + 1] = f2.y;
    }

    // ---- geo MLP: 32 -> 64 -> 64 -> 16 ----
    float h0[64], h1[64], geo[16];
    dense_layer<32, 64, true >(feats, Wg0, bg0, h0);
    dense_layer<64, 64, true >(h0,    Wg1, bg1, h1);
    dense_layer<64, 16, false>(h1,    Wd,  bd,  geo);

    // density = softplus(geo[0] - 1)
    const float gx = geo[0] - 1.0f;
    const float density = fmaxf(gx, 0.0f) + log1pf(expf(-fabsf(gx)));

    // ---- color MLP input: [geo[1:16], sh(dir)] ----
    float c0[64], c1[64], c2[64], col[3];
    {
        float cin[24];
#pragma unroll
        for (int i = 0; i < 15; ++i) cin[i] = geo[1 + i];
        cin[15] = 0.5f;
        cin[16] = dx;  cin[17] = dy;  cin[18] = dz;
        cin[19] = dx * dy;  cin[20] = dx * dz;  cin[21] = dy * dz;
        cin[22] = dx * dx - dy * dy;
        cin[23] = 3.0f * dz * dz - 1.0f;
        dense_layer<24, 64, true >(cin, Wc0, bc0, c0);
    }
    dense_layer<64, 64, true >(c0, Wc1, bc1, c1);
    dense_layer<64, 64, true >(c1, Wc2, bc2, c2);
    dense_layer<64, 3,  false>(c2, Wch, bch, col);
#pragma unroll
    for (int c = 0; c < 3; ++c) col[c] = 1.0f / (1.0f + expf(-col[c]));

    // ---- volume rendering ----
    const float dnorm = sqrtf(dx * dx + dy * dy + dz * dz);
    float dist = (lane < 63) ? (zn - z) : 1e10f;
    dist *= dnorm;
    const float alpha = 1.0f - expf(-density * dist);

    // inclusive product scan of (1 - alpha + 1e-10), then shift for exclusive T
    float f = 1.0f - alpha + 1e-10f;
#pragma unroll
    for (int off = 1; off < 64; off <<= 1) {
        const float g = __shfl_up(f, off, 64);
        if (lane >= off) f *= g;
    }
    float T = __shfl_up(f, 1, 64);
    if (lane == 0) T = 1.0f;
    const float w = alpha * T;

    // weights output (coalesced per wave)
    out[kOffWeights + ray * 64 + lane] = w;

    const float sr = wave_sum(w * col[0]);
    const float sg = wave_sum(w * col[1]);
    const float sb = wave_sum(w * col[2]);
    const float sd = wave_sum(w * z);
    const float sa = wave_sum(w);
    if (lane == 0) {
        out[ray * 3 + 0] = sr;
        out[ray * 3 + 1] = sg;
        out[ray * 3 + 2] = sb;
        out[kOffDepth + ray] = sd;
        out[kOffAcc   + ray] = sa;
    }
}

extern "C" void kernel_launch(void* const* d_in, const int* in_sizes, int n_in,
                              void* d_out, int out_size, void* d_ws, size_t ws_size,
                              hipStream_t stream) {
    const float* rays_o = (const float*)d_in[0];
    const float* rays_d = (const float*)d_in[1];
    const float* tables = (const float*)d_in[2];
    const float* Wg0 = (const float*)d_in[3];
    const float* bg0 = (const float*)d_in[4];
    const float* Wg1 = (const float*)d_in[5];
    const float* bg1 = (const float*)d_in[6];
    const float* Wd  = (const float*)d_in[7];
    const float* bd  = (const float*)d_in[8];
    const float* Wc0 = (const float*)d_in[9];
    const float* bc0 = (const float*)d_in[10];
    const float* Wc1 = (const float*)d_in[11];
    const float* bc1 = (const float*)d_in[12];
    const float* Wc2 = (const float*)d_in[13];
    const float* bc2 = (const float*)d_in[14];
    const float* Wch = (const float*)d_in[15];
    const float* bch = (const float*)d_in[16];
    float* out = (float*)d_out;

    nerf_fused_kernel<<<dim3(kNRays / 4), dim3(256), 0, stream>>>(
        rays_o, rays_d, tables,
        Wg0, bg0, Wg1, bg1, Wd, bd,
        Wc0, bc0, Wc1, bc1, Wc2, bc2, Wch, bch,
        out);
}

// Round 2
// 165.714 us; speedup vs baseline: 3.3045x; 3.3045x over previous
//
#include <hip/hip_runtime.h>
#include <math.h>

typedef float  f32x4 __attribute__((ext_vector_type(4)));
typedef short  s16x8 __attribute__((ext_vector_type(8)));
typedef unsigned int u32x2 __attribute__((ext_vector_type(2)));
typedef unsigned int u32x4 __attribute__((ext_vector_type(4)));

constexpr int kNRays = 16384;
constexpr int kTableSize = 1 << 19;
constexpr int kOffDepth   = kNRays * 3;
constexpr int kOffAcc     = kOffDepth + kNRays;
constexpr int kOffWeights = kOffAcc + kNRays;

// LDS (ushort units): A-fragment region [0,11264), then 4 per-wave X buffers (64 cols x 64 rows, swizzled)
constexpr int kAHw = 11264;
constexpr int kXHw = 4096;

__device__ __forceinline__ ushort f2bf(float x) {
    unsigned u = __float_as_uint(x);
    return (ushort)((u + 0x7FFFu + ((u >> 16) & 1u)) >> 16);
}
__device__ __forceinline__ unsigned pk2(float lo, float hi) {
    return (unsigned)f2bf(lo) | ((unsigned)f2bf(hi) << 16);
}
__device__ __forceinline__ float sel4(float v0, float v1, float v2, float v3, int s) {
    float a = (s & 1) ? v1 : v0;
    float b = (s & 1) ? v3 : v2;
    return (s & 2) ? b : a;
}
__device__ __forceinline__ float wave_sum(float v) {
#pragma unroll
    for (int off = 32; off > 0; off >>= 1) v += __shfl_xor(v, off, 64);
    return v;
}

// Stage W (global f32, [FIN][FOUT] row-major) into LDS as bf16 A-fragments:
// elem i -> tile t=i>>9 (kt=t%KT, mt=t/KT), lane l=(i>>3)&63, e=i&7
// value = W[kt*32 + (l>>4)*8 + e][mt*16 + (l&15)]  (zero-padded outside FIN/FOUT)
__device__ __forceinline__ void stageA(ushort* dst, const float* __restrict__ W,
                                       int FIN, int FOUT, int KT, int MT, int tid, bool dperm) {
    const int total = MT * KT * 512;
    for (int i = tid; i < total; i += 256) {
        int e = i & 7, l = (i >> 3) & 63, t = i >> 9;
        int kt = t % KT, mt = t / KT;
        int k = kt * 32 + ((l >> 4) << 3) + e;
        int j = mt * 16 + (l & 15);
        if (dperm) j = (j == 15) ? 0 : j + 1;   // d-layer: rotate cols so geo[0] lands at row 15
        float w = 0.0f;
        if (k < FIN && j < FOUT) w = W[k * FOUT + j];
        dst[i] = f2bf(w);
    }
}

// B fragment read + MFMA over MT x 4 x KT tiles. X is column-major bf16, 64 hw per col,
// 16B blocks XOR-swizzled by (col&7).
template<int KT, int MT>
__device__ __forceinline__ void mfma_layer(const ushort* Xw, const ushort* Al,
                                           int c16, int g, int lane, f32x4 acc[MT][4]) {
    s16x8 B[KT][4];
#pragma unroll
    for (int kt = 0; kt < KT; ++kt)
#pragma unroll
        for (int nt = 0; nt < 4; ++nt) {
            const int col = nt * 16 + c16;
            B[kt][nt] = *(const s16x8*)&Xw[col * 64 + 8 * ((kt * 4 + g) ^ (c16 & 7))];
        }
#pragma unroll
    for (int mt = 0; mt < MT; ++mt) {
        const s16x8 A0 = *(const s16x8*)&Al[((mt * KT + 0) * 64 + lane) * 8];
        s16x8 A1;
        if constexpr (KT == 2) A1 = *(const s16x8*)&Al[((mt * KT + 1) * 64 + lane) * 8];
#pragma unroll
        for (int nt = 0; nt < 4; ++nt) {
            acc[mt][nt] = __builtin_amdgcn_mfma_f32_16x16x32_bf16(A0, B[0][nt], acc[mt][nt], 0, 0, 0);
            if constexpr (KT == 2)
                acc[mt][nt] = __builtin_amdgcn_mfma_f32_16x16x32_bf16(A1, B[1][nt], acc[mt][nt], 0, 0, 0);
        }
    }
}

// Write D tiles back to X (bf16, optional ReLU). Row0 = mt*16+g*4 -> block j=2mt+(g>>1), 8B offset 4*(g&1) hw.
template<int MT, bool RELU>
__device__ __forceinline__ void store_acts(ushort* Xw, int c16, int g, f32x4 acc[MT][4]) {
#pragma unroll
    for (int mt = 0; mt < MT; ++mt)
#pragma unroll
        for (int nt = 0; nt < 4; ++nt) {
            const int col = nt * 16 + c16;
            f32x4 v = acc[mt][nt];
            float x0 = v.x, x1 = v.y, x2 = v.z, x3 = v.w;
            if (RELU) {
                x0 = fmaxf(x0, 0.f); x1 = fmaxf(x1, 0.f);
                x2 = fmaxf(x2, 0.f); x3 = fmaxf(x3, 0.f);
            }
            const int a = col * 64 + 8 * ((2 * mt + (g >> 1)) ^ (c16 & 7)) + 4 * (g & 1);
            *(u32x2*)&Xw[a] = (u32x2){ pk2(x0, x1), pk2(x2, x3) };
        }
}

__global__ __launch_bounds__(256, 2) void nerf_mfma_kernel(
    const float* __restrict__ rays_o, const float* __restrict__ rays_d,
    const float* __restrict__ tables,
    const float* __restrict__ Wg0, const float* __restrict__ bg0,
    const float* __restrict__ Wg1, const float* __restrict__ bg1,
    const float* __restrict__ Wd,  const float* __restrict__ bd,
    const float* __restrict__ Wc0, const float* __restrict__ bc0,
    const float* __restrict__ Wc1, const float* __restrict__ bc1,
    const float* __restrict__ Wc2, const float* __restrict__ bc2,
    const float* __restrict__ Wch, const float* __restrict__ bch,
    float* __restrict__ out)
{
    __shared__ __align__(16) ushort smem[kAHw + 4 * kXHw];
    const int tid  = threadIdx.x;
    const int wid  = tid >> 6;
    const int lane = tid & 63;
    const int c16  = lane & 15;
    const int g    = lane >> 4;
    const int ray  = blockIdx.x * 4 + wid;
    ushort* Xw = smem + kAHw + wid * kXHw;

    const float ox = rays_o[ray * 3 + 0], oy = rays_o[ray * 3 + 1], oz = rays_o[ray * 3 + 2];
    const float dx = rays_d[ray * 3 + 0], dy = rays_d[ray * 3 + 1], dz = rays_d[ray * 3 + 2];

    const float step = 1.0f / 63.0f;
    const float z  = 0.1f + 1.4f * ((float)lane * step);
    const float zn = 0.1f + 1.4f * ((float)(lane + 1) * step);
    const float px = ox + dx * z, py = oy + dy * z, pz = oz + dz * z;

    // ---- hash gather: lane = sample = X column; pack 32 feats to bf16 pairs ----
    unsigned pk[16];
#pragma unroll
    for (int l = 0; l < 16; ++l) {
        const float res = (float)(32 << l);
        const float rm1 = res - 1.0f;
        float sx = (px + 1.0f) * 0.5f * rm1; sx = fminf(fmaxf(sx, 0.f), rm1);
        float sy = (py + 1.0f) * 0.5f * rm1; sy = fminf(fmaxf(sy, 0.f), rm1);
        float sz = (pz + 1.0f) * 0.5f * rm1; sz = fminf(fmaxf(sz, 0.f), rm1);
        const float idxf = sx * res * res + sy * res + sz;
        const float szm1 = (l == 0) ? 32767.f : (l == 1) ? 262143.f : 524287.f;
        const int idx = (int)fminf(idxf, szm1);
        const float2 f2 = *reinterpret_cast<const float2*>(
            tables + ((size_t)l * kTableSize + (size_t)idx) * 2);
        pk[l] = pk2(f2.x, f2.y);
    }
#pragma unroll
    for (int j = 0; j < 4; ++j) {
        u32x4 w = { pk[4 * j], pk[4 * j + 1], pk[4 * j + 2], pk[4 * j + 3] };
        *(u32x4*)&Xw[lane * 64 + 8 * (j ^ (lane & 7))] = w;
    }

    // ---- phase 1: geo weights -> A region ----
    stageA(smem,        Wg0, 32, 64, 1, 4, tid, false);
    stageA(smem + 2048, Wg1, 64, 64, 2, 4, tid, false);
    stageA(smem + 6144, Wd,  64, 16, 2, 1, tid, true);
    __syncthreads();

    f32x4 acc[4][4];
    // g0: 32 -> 64, relu
#pragma unroll
    for (int mt = 0; mt < 4; ++mt) {
        f32x4 b = *(const f32x4*)(bg0 + mt * 16 + g * 4);
#pragma unroll
        for (int nt = 0; nt < 4; ++nt) acc[mt][nt] = b;
    }
    mfma_layer<1, 4>(Xw, smem, c16, g, lane, acc);
    store_acts<4, true>(Xw, c16, g, acc);
    // g1: 64 -> 64, relu
#pragma unroll
    for (int mt = 0; mt < 4; ++mt) {
        f32x4 b = *(const f32x4*)(bg1 + mt * 16 + g * 4);
#pragma unroll
        for (int nt = 0; nt < 4; ++nt) acc[mt][nt] = b;
    }
    mfma_layer<2, 4>(Xw, smem + 2048, c16, g, lane, acc);
    store_acts<4, true>(Xw, c16, g, acc);
    // d: 64 -> 16 (cols permuted: rows 0..14 = geo[1..15], row 15 = geo[0])
    f32x4 accd[1][4];
    {
        const float db0 = bd[g * 4 + 1];
        const float db1 = bd[g * 4 + 2];
        const float db2 = bd[g * 4 + 3];
        const int i3 = (g == 3) ? 0 : g * 4 + 4;
        const float db3 = bd[i3];
        f32x4 b = { db0, db1, db2, db3 };
#pragma unroll
        for (int nt = 0; nt < 4; ++nt) accd[0][nt] = b;
    }
    mfma_layer<2, 1>(Xw, smem + 6144, c16, g, lane, accd);
    // density logit = D row 15 (source lane 48+c16, reg .w), col selected by this lane's g
    const float lgit = sel4(__shfl(accd[0][0].w, 48 + c16, 64),
                            __shfl(accd[0][1].w, 48 + c16, 64),
                            __shfl(accd[0][2].w, 48 + c16, 64),
                            __shfl(accd[0][3].w, 48 + c16, 64), g);
    store_acts<1, false>(Xw, c16, g, accd);            // c_in rows 0..15 (row 15 = junk logit)
    Xw[lane * 64 + 8 * (1 ^ (lane & 7)) + 7] = 0x3F00; // row 15 := bf16(0.5)
    {   // SH rows 16..23 (per-ray uniform)
        u32x4 w = { pk2(dx, dy), pk2(dz, dx * dy), pk2(dx * dz, dy * dz),
                    pk2(dx * dx - dy * dy, 3.f * dz * dz - 1.f) };
        *(u32x4*)&Xw[lane * 64 + 8 * (2 ^ (lane & 7))] = w;
    }

    // ---- phase 2: color weights -> A region ----
    __syncthreads();
    stageA(smem,         Wc0, 24, 64, 1, 4, tid, false); // K rows 24..31 zeroed on A side
    stageA(smem + 2048,  Wc1, 64, 64, 2, 4, tid, false);
    stageA(smem + 6144,  Wc2, 64, 64, 2, 4, tid, false);
    stageA(smem + 10240, Wch, 64, 3,  2, 1, tid, false);
    __syncthreads();

    // c0: 24(pad 32) -> 64, relu
#pragma unroll
    for (int mt = 0; mt < 4; ++mt) {
        f32x4 b = *(const f32x4*)(bc0 + mt * 16 + g * 4);
#pragma unroll
        for (int nt = 0; nt < 4; ++nt) acc[mt][nt] = b;
    }
    mfma_layer<1, 4>(Xw, smem, c16, g, lane, acc);
    store_acts<4, true>(Xw, c16, g, acc);
    // c1
#pragma unroll
    for (int mt = 0; mt < 4; ++mt) {
        f32x4 b = *(const f32x4*)(bc1 + mt * 16 + g * 4);
#pragma unroll
        for (int nt = 0; nt < 4; ++nt) acc[mt][nt] = b;
    }
    mfma_layer<2, 4>(Xw, smem + 2048, c16, g, lane, acc);
    store_acts<4, true>(Xw, c16, g, acc);
    // c2
#pragma unroll
    for (int mt = 0; mt < 4; ++mt) {
        f32x4 b = *(const f32x4*)(bc2 + mt * 16 + g * 4);
#pragma unroll
        for (int nt = 0; nt < 4; ++nt) acc[mt][nt] = b;
    }
    mfma_layer<2, 4>(Xw, smem + 6144, c16, g, lane, acc);
    store_acts<4, true>(Xw, c16, g, acc);
    // ch: 64 -> 3 (rows 3..15 padding)
    f32x4 accc[1][4];
    {
        const float cb0 = bch[0], cb1 = bch[1], cb2 = bch[2];
        f32x4 b = (g == 0) ? (f32x4){ cb0, cb1, cb2, 0.f } : (f32x4){ 0.f, 0.f, 0.f, 0.f };
#pragma unroll
        for (int nt = 0; nt < 4; ++nt) accc[0][nt] = b;
    }
    mfma_layer<2, 1>(Xw, smem + 10240, c16, g, lane, accc);
    // color logits: rows 0..2 live in source lane c16 (g=0), regs .x/.y/.z
    const float lr = sel4(__shfl(accc[0][0].x, c16, 64), __shfl(accc[0][1].x, c16, 64),
                          __shfl(accc[0][2].x, c16, 64), __shfl(accc[0][3].x, c16, 64), g);
    const float lgr = sel4(__shfl(accc[0][0].y, c16, 64), __shfl(accc[0][1].y, c16, 64),
                           __shfl(accc[0][2].y, c16, 64), __shfl(accc[0][3].y, c16, 64), g);
    const float lb = sel4(__shfl(accc[0][0].z, c16, 64), __shfl(accc[0][1].z, c16, 64),
                          __shfl(accc[0][2].z, c16, 64), __shfl(accc[0][3].z, c16, 64), g);

    const float cr = 1.f / (1.f + expf(-lr));
    const float cg = 1.f / (1.f + expf(-lgr));
    const float cb = 1.f / (1.f + expf(-lb));
    const float gx = lgit - 1.0f;
    const float density = fmaxf(gx, 0.f) + log1pf(expf(-fabsf(gx)));

    // ---- volume rendering ----
    const float dnorm = sqrtf(dx * dx + dy * dy + dz * dz);
    float dist = (lane < 63) ? (zn - z) : 1e10f;
    dist *= dnorm;
    const float alpha = 1.0f - expf(-density * dist);
    float f = 1.0f - alpha + 1e-10f;
#pragma unroll
    for (int off = 1; off < 64; off <<= 1) {
        const float gg = __shfl_up(f, off, 64);
        if (lane >= off) f *= gg;
    }
    float T = __shfl_up(f, 1, 64);
    if (lane == 0) T = 1.0f;
    const float w = alpha * T;

    out[kOffWeights + ray * 64 + lane] = w;
    const float sr = wave_sum(w * cr);
    const float sg = wave_sum(w * cg);
    const float sb = wave_sum(w * cb);
    const float sd = wave_sum(w * z);
    const float sa = wave_sum(w);
    if (lane == 0) {
        out[ray * 3 + 0] = sr;
        out[ray * 3 + 1] = sg;
        out[ray * 3 + 2] = sb;
        out[kOffDepth + ray] = sd;
        out[kOffAcc + ray]   = sa;
    }
}

extern "C" void kernel_launch(void* const* d_in, const int* in_sizes, int n_in,
                              void* d_out, int out_size, void* d_ws, size_t ws_size,
                              hipStream_t stream) {
    const float* rays_o = (const float*)d_in[0];
    const float* rays_d = (const float*)d_in[1];
    const float* tables = (const float*)d_in[2];
    const float* Wg0 = (const float*)d_in[3];
    const float* bg0 = (const float*)d_in[4];
    const float* Wg1 = (const float*)d_in[5];
    const float* bg1 = (const float*)d_in[6];
    const float* Wd  = (const float*)d_in[7];
    const float* bd  = (const float*)d_in[8];
    const float* Wc0 = (const float*)d_in[9];
    const float* bc0 = (const float*)d_in[10];
    const float* Wc1 = (const float*)d_in[11];
    const float* bc1 = (const float*)d_in[12];
    const float* Wc2 = (const float*)d_in[13];
    const float* bc2 = (const float*)d_in[14];
    const float* Wch = (const float*)d_in[15];
    const float* bch = (const float*)d_in[16];
    float* out = (float*)d_out;

    nerf_mfma_kernel<<<dim3(kNRays / 4), dim3(256), 0, stream>>>(
        rays_o, rays_d, tables,
        Wg0, bg0, Wg1, bg1, Wd, bd,
        Wc0, bc0, Wc1, bc1, Wc2, bc2, Wch, bch,
        out);
}

// Round 3
// 107.741 us; speedup vs baseline: 5.0826x; 1.5381x over previous
//
#include <hip/hip_runtime.h>
#include <math.h>

typedef float  f32x4 __attribute__((ext_vector_type(4)));
typedef short  s16x8 __attribute__((ext_vector_type(8)));
typedef unsigned int u32x2 __attribute__((ext_vector_type(2)));
typedef unsigned int u32x4 __attribute__((ext_vector_type(4)));

constexpr int kNRays = 16384;
constexpr int kTableSize = 1 << 19;
constexpr int kOffDepth   = kNRays * 3;
constexpr int kOffAcc     = kOffDepth + kNRays;
constexpr int kOffWeights = kOffAcc + kNRays;

// Pre-staged A-fragment regions in d_ws (ushort offsets)
constexpr int kWg0 = 0;      // 32x64  KT=1 MT=4 -> 2048
constexpr int kWg1 = 2048;   // 64x64  KT=2 MT=4 -> 4096
constexpr int kWd  = 6144;   // 64x16  KT=2 MT=1 -> 1024 (dperm)
constexpr int kWc0 = 7168;   // 24x64  KT=1 MT=4 -> 2048
constexpr int kWc1 = 9216;   // 64x64  -> 4096
constexpr int kWc2 = 13312;  // 64x64  -> 4096
constexpr int kWch = 17408;  // 64x3   KT=2 MT=1 -> 1024
constexpr int kWsTotal = 18432;

__device__ __forceinline__ ushort f2bf(float x) {
    unsigned u = __float_as_uint(x);
    return (ushort)((u + 0x7FFFu + ((u >> 16) & 1u)) >> 16);
}
__device__ __forceinline__ unsigned pk2(float lo, float hi) {
    return (unsigned)f2bf(lo) | ((unsigned)f2bf(hi) << 16);
}
__device__ __forceinline__ float sel4(float v0, float v1, float v2, float v3, int s) {
    float a = (s & 1) ? v1 : v0;
    float b = (s & 1) ? v3 : v2;
    return (s & 2) ? b : a;
}
__device__ __forceinline__ float wave_sum(float v) {
#pragma unroll
    for (int off = 32; off > 0; off >>= 1) v += __shfl_xor(v, off, 64);
    return v;
}

// One-time weight staging: W (f32 [FIN][FOUT]) -> bf16 A-fragments in ws.
// elem i in region: e=i&7, l=(i>>3)&63, t=i>>9 (kt=t%KT, mt=t/KT)
// value = W[kt*32 + (l>>4)*8 + e][mt*16 + (l&15)], zero-padded.
__global__ __launch_bounds__(256) void prep_weights(
    const float* __restrict__ Wg0, const float* __restrict__ Wg1,
    const float* __restrict__ Wd,  const float* __restrict__ Wc0,
    const float* __restrict__ Wc1, const float* __restrict__ Wc2,
    const float* __restrict__ Wch, ushort* __restrict__ ws)
{
    const int i = blockIdx.x * 256 + threadIdx.x;
    if (i >= kWsTotal) return;
    const float* W; int FIN, FOUT, KT, base; bool dperm = false;
    if (i < kWg1)      { W = Wg0; FIN = 32; FOUT = 64; KT = 1; base = kWg0; }
    else if (i < kWd)  { W = Wg1; FIN = 64; FOUT = 64; KT = 2; base = kWg1; }
    else if (i < kWc0) { W = Wd;  FIN = 64; FOUT = 16; KT = 2; base = kWd; dperm = true; }
    else if (i < kWc1) { W = Wc0; FIN = 24; FOUT = 64; KT = 1; base = kWc0; }
    else if (i < kWc2) { W = Wc1; FIN = 64; FOUT = 64; KT = 2; base = kWc1; }
    else if (i < kWch) { W = Wc2; FIN = 64; FOUT = 64; KT = 2; base = kWc2; }
    else               { W = Wch; FIN = 64; FOUT = 3;  KT = 2; base = kWch; }
    const int r = i - base;
    const int e = r & 7, l = (r >> 3) & 63, t = r >> 9;
    const int kt = t % KT, mt = t / KT;
    const int k = kt * 32 + ((l >> 4) << 3) + e;
    int j = mt * 16 + (l & 15);
    if (dperm) j = (j == 15) ? 0 : j + 1;   // d-layer: geo[0] -> row 15, geo[1..15] -> rows 0..14
    float w = 0.0f;
    if (k < FIN && j < FOUT) w = W[k * FOUT + j];
    ws[i] = f2bf(w);
}

// B from per-wave LDS X (col-major bf16, 16B blocks XOR-swizzled by col&7),
// A from pre-staged global fragments.
template<int KT, int MT>
__device__ __forceinline__ void mfma_layer(const ushort* Xw, const ushort* __restrict__ Aws,
                                           int c16, int g, int lane, f32x4 acc[MT][4]) {
    s16x8 A[MT][KT];
#pragma unroll
    for (int mt = 0; mt < MT; ++mt)
#pragma unroll
        for (int kt = 0; kt < KT; ++kt)
            A[mt][kt] = *(const s16x8*)&Aws[((mt * KT + kt) * 64 + lane) * 8];
    s16x8 B[KT][4];
#pragma unroll
    for (int kt = 0; kt < KT; ++kt)
#pragma unroll
        for (int nt = 0; nt < 4; ++nt) {
            const int col = nt * 16 + c16;
            B[kt][nt] = *(const s16x8*)&Xw[col * 64 + 8 * ((kt * 4 + g) ^ (c16 & 7))];
        }
#pragma unroll
    for (int mt = 0; mt < MT; ++mt)
#pragma unroll
        for (int nt = 0; nt < 4; ++nt) {
            acc[mt][nt] = __builtin_amdgcn_mfma_f32_16x16x32_bf16(A[mt][0], B[0][nt], acc[mt][nt], 0, 0, 0);
            if constexpr (KT == 2)
                acc[mt][nt] = __builtin_amdgcn_mfma_f32_16x16x32_bf16(A[mt][1], B[1][nt], acc[mt][nt], 0, 0, 0);
        }
}

template<int MT, bool RELU>
__device__ __forceinline__ void store_acts(ushort* Xw, int c16, int g, f32x4 acc[MT][4]) {
#pragma unroll
    for (int mt = 0; mt < MT; ++mt)
#pragma unroll
        for (int nt = 0; nt < 4; ++nt) {
            const int col = nt * 16 + c16;
            f32x4 v = acc[mt][nt];
            float x0 = v.x, x1 = v.y, x2 = v.z, x3 = v.w;
            if (RELU) {
                x0 = fmaxf(x0, 0.f); x1 = fmaxf(x1, 0.f);
                x2 = fmaxf(x2, 0.f); x3 = fmaxf(x3, 0.f);
            }
            const int a = col * 64 + 8 * ((2 * mt + (g >> 1)) ^ (c16 & 7)) + 4 * (g & 1);
            *(u32x2*)&Xw[a] = (u32x2){ pk2(x0, x1), pk2(x2, x3) };
        }
}

__global__ __launch_bounds__(256, 4) void nerf_mfma_kernel(
    const float* __restrict__ rays_o, const float* __restrict__ rays_d,
    const float* __restrict__ tables, const ushort* __restrict__ ws,
    const float* __restrict__ bg0, const float* __restrict__ bg1,
    const float* __restrict__ bd,  const float* __restrict__ bc0,
    const float* __restrict__ bc1, const float* __restrict__ bc2,
    const float* __restrict__ bch, float* __restrict__ out)
{
    __shared__ __align__(16) ushort Xs[4 * 4096];
    const int tid  = threadIdx.x;
    const int wid  = tid >> 6;
    const int lane = tid & 63;
    const int c16  = lane & 15;
    const int g    = lane >> 4;
    const int ray  = blockIdx.x * 4 + wid;
    ushort* Xw = Xs + wid * 4096;

    const float ox = rays_o[ray * 3 + 0], oy = rays_o[ray * 3 + 1], oz = rays_o[ray * 3 + 2];
    const float dx = rays_d[ray * 3 + 0], dy = rays_d[ray * 3 + 1], dz = rays_d[ray * 3 + 2];

    const float step = 1.0f / 63.0f;
    const float z  = 0.1f + 1.4f * ((float)lane * step);
    const float zn = 0.1f + 1.4f * ((float)(lane + 1) * step);

    // ---- input-layer B fragments straight from the hash gather ----
    // lane (g,c16), tile nt: sample s = nt*16+c16, levels g*4+j (j=0..3)
    s16x8 B0[4];
#pragma unroll
    for (int nt = 0; nt < 4; ++nt) {
        const int s = nt * 16 + c16;
        const float zs = 0.1f + 1.4f * ((float)s * step);
        const float px = ox + dx * zs, py = oy + dy * zs, pz = oz + dz * zs;
        u32x4 val;
#pragma unroll
        for (int j = 0; j < 4; ++j) {
            const int lv = g * 4 + j;
            const float res = (float)(32 << lv);
            const float rm1 = res - 1.0f;
            float sx = (px + 1.0f) * 0.5f * rm1; sx = fminf(fmaxf(sx, 0.f), rm1);
            float sy = (py + 1.0f) * 0.5f * rm1; sy = fminf(fmaxf(sy, 0.f), rm1);
            float sz = (pz + 1.0f) * 0.5f * rm1; sz = fminf(fmaxf(sz, 0.f), rm1);
            const float idxf = sx * res * res + sy * res + sz;
            const float szm1 = (lv == 0) ? 32767.f : (lv == 1) ? 262143.f : 524287.f;
            const int idx = (int)fminf(idxf, szm1);
            const float2 f2 = *reinterpret_cast<const float2*>(
                tables + ((size_t)lv * kTableSize + (size_t)idx) * 2);
            val[j] = pk2(f2.x, f2.y);
        }
        B0[nt] = *(const s16x8*)&val;
    }

    f32x4 acc[4][4];
    // ---- g0: 32 -> 64, relu (A from ws, B direct) ----
#pragma unroll
    for (int mt = 0; mt < 4; ++mt) {
        const s16x8 A0 = *(const s16x8*)&ws[kWg0 + (mt * 64 + lane) * 8];
        f32x4 b = *(const f32x4*)(bg0 + mt * 16 + g * 4);
#pragma unroll
        for (int nt = 0; nt < 4; ++nt) {
            acc[mt][nt] = b;
            acc[mt][nt] = __builtin_amdgcn_mfma_f32_16x16x32_bf16(A0, B0[nt], acc[mt][nt], 0, 0, 0);
        }
    }
    store_acts<4, true>(Xw, c16, g, acc);

    // ---- g1: 64 -> 64, relu ----
#pragma unroll
    for (int mt = 0; mt < 4; ++mt) {
        f32x4 b = *(const f32x4*)(bg1 + mt * 16 + g * 4);
#pragma unroll
        for (int nt = 0; nt < 4; ++nt) acc[mt][nt] = b;
    }
    mfma_layer<2, 4>(Xw, ws + kWg1, c16, g, lane, acc);
    store_acts<4, true>(Xw, c16, g, acc);

    // ---- d: 64 -> 16 (cols rotated: rows 0..14 = geo[1..15], row 15 = geo[0]) ----
    f32x4 accd[1][4];
    {
        const float db0 = bd[g * 4 + 1];
        const float db1 = bd[g * 4 + 2];
        const float db2 = bd[g * 4 + 3];
        const int i3 = (g == 3) ? 0 : g * 4 + 4;
        const float db3 = bd[i3];
        f32x4 b = { db0, db1, db2, db3 };
#pragma unroll
        for (int nt = 0; nt < 4; ++nt) accd[0][nt] = b;
    }
    mfma_layer<2, 1>(Xw, ws + kWd, c16, g, lane, accd);
    const float lgit = sel4(__shfl(accd[0][0].w, 48 + c16, 64),
                            __shfl(accd[0][1].w, 48 + c16, 64),
                            __shfl(accd[0][2].w, 48 + c16, 64),
                            __shfl(accd[0][3].w, 48 + c16, 64), g);
    store_acts<1, false>(Xw, c16, g, accd);            // c_in rows 0..15 (row15 junk)
    Xw[lane * 64 + 8 * (1 ^ (lane & 7)) + 7] = 0x3F00; // row 15 := bf16(0.5)
    {   // SH rows 16..23 (per-ray uniform)
        u32x4 w = { pk2(dx, dy), pk2(dz, dx * dy), pk2(dx * dz, dy * dz),
                    pk2(dx * dx - dy * dy, 3.f * dz * dz - 1.f) };
        *(u32x4*)&Xw[lane * 64 + 8 * (2 ^ (lane & 7))] = w;
    }

    // ---- c0: 24(pad32) -> 64, relu ----
#pragma unroll
    for (int mt = 0; mt < 4; ++mt) {
        f32x4 b = *(const f32x4*)(bc0 + mt * 16 + g * 4);
#pragma unroll
        for (int nt = 0; nt < 4; ++nt) acc[mt][nt] = b;
    }
    mfma_layer<1, 4>(Xw, ws + kWc0, c16, g, lane, acc);
    store_acts<4, true>(Xw, c16, g, acc);
    // ---- c1 ----
#pragma unroll
    for (int mt = 0; mt < 4; ++mt) {
        f32x4 b = *(const f32x4*)(bc1 + mt * 16 + g * 4);
#pragma unroll
        for (int nt = 0; nt < 4; ++nt) acc[mt][nt] = b;
    }
    mfma_layer<2, 4>(Xw, ws + kWc1, c16, g, lane, acc);
    store_acts<4, true>(Xw, c16, g, acc);
    // ---- c2 ----
#pragma unroll
    for (int mt = 0; mt < 4; ++mt) {
        f32x4 b = *(const f32x4*)(bc2 + mt * 16 + g * 4);
#pragma unroll
        for (int nt = 0; nt < 4; ++nt) acc[mt][nt] = b;
    }
    mfma_layer<2, 4>(Xw, ws + kWc2, c16, g, lane, acc);
    store_acts<4, true>(Xw, c16, g, acc);
    // ---- ch: 64 -> 3 ----
    f32x4 accc[1][4];
    {
        const float cb0 = bch[0], cb1 = bch[1], cb2 = bch[2];
        f32x4 b = (g == 0) ? (f32x4){ cb0, cb1, cb2, 0.f } : (f32x4){ 0.f, 0.f, 0.f, 0.f };
#pragma unroll
        for (int nt = 0; nt < 4; ++nt) accc[0][nt] = b;
    }
    mfma_layer<2, 1>(Xw, ws + kWch, c16, g, lane, accc);
    const float lr = sel4(__shfl(accc[0][0].x, c16, 64), __shfl(accc[0][1].x, c16, 64),
                          __shfl(accc[0][2].x, c16, 64), __shfl(accc[0][3].x, c16, 64), g);
    const float lgr = sel4(__shfl(accc[0][0].y, c16, 64), __shfl(accc[0][1].y, c16, 64),
                           __shfl(accc[0][2].y, c16, 64), __shfl(accc[0][3].y, c16, 64), g);
    const float lb = sel4(__shfl(accc[0][0].z, c16, 64), __shfl(accc[0][1].z, c16, 64),
                          __shfl(accc[0][2].z, c16, 64), __shfl(accc[0][3].z, c16, 64), g);

    const float cr = 1.f / (1.f + expf(-lr));
    const float cg = 1.f / (1.f + expf(-lgr));
    const float cb = 1.f / (1.f + expf(-lb));
    const float gx = lgit - 1.0f;
    const float density = fmaxf(gx, 0.f) + log1pf(expf(-fabsf(gx)));

    // ---- volume rendering ----
    const float dnorm = sqrtf(dx * dx + dy * dy + dz * dz);
    float dist = (lane < 63) ? (zn - z) : 1e10f;
    dist *= dnorm;
    const float alpha = 1.0f - expf(-density * dist);
    float f = 1.0f - alpha + 1e-10f;
#pragma unroll
    for (int off = 1; off < 64; off <<= 1) {
        const float gg = __shfl_up(f, off, 64);
        if (lane >= off) f *= gg;
    }
    float T = __shfl_up(f, 1, 64);
    if (lane == 0) T = 1.0f;
    const float w = alpha * T;

    out[kOffWeights + ray * 64 + lane] = w;
    const float sr = wave_sum(w * cr);
    const float sg = wave_sum(w * cg);
    const float sb = wave_sum(w * cb);
    const float sd = wave_sum(w * z);
    const float sa = wave_sum(w);
    if (lane == 0) {
        out[ray * 3 + 0] = sr;
        out[ray * 3 + 1] = sg;
        out[ray * 3 + 2] = sb;
        out[kOffDepth + ray] = sd;
        out[kOffAcc + ray]   = sa;
    }
}

extern "C" void kernel_launch(void* const* d_in, const int* in_sizes, int n_in,
                              void* d_out, int out_size, void* d_ws, size_t ws_size,
                              hipStream_t stream) {
    const float* rays_o = (const float*)d_in[0];
    const float* rays_d = (const float*)d_in[1];
    const float* tables = (const float*)d_in[2];
    const float* Wg0 = (const float*)d_in[3];
    const float* bg0 = (const float*)d_in[4];
    const float* Wg1 = (const float*)d_in[5];
    const float* bg1 = (const float*)d_in[6];
    const float* Wd  = (const float*)d_in[7];
    const float* bd  = (const float*)d_in[8];
    const float* Wc0 = (const float*)d_in[9];
    const float* bc0 = (const float*)d_in[10];
    const float* Wc1 = (const float*)d_in[11];
    const float* bc1 = (const float*)d_in[12];
    const float* Wc2 = (const float*)d_in[13];
    const float* bc2 = (const float*)d_in[14];
    const float* Wch = (const float*)d_in[15];
    const float* bch = (const float*)d_in[16];
    float* out = (float*)d_out;
    ushort* wsp = (ushort*)d_ws;

    prep_weights<<<dim3((kWsTotal + 255) / 256), dim3(256), 0, stream>>>(
        Wg0, Wg1, Wd, Wc0, Wc1, Wc2, Wch, wsp);

    nerf_mfma_kernel<<<dim3(kNRays / 4), dim3(256), 0, stream>>>(
        rays_o, rays_d, tables, wsp,
        bg0, bg1, bd, bc0, bc1, bc2, bch, out);
}

// Round 4
// 80.554 us; speedup vs baseline: 6.7980x; 1.3375x over previous
//
#include <hip/hip_runtime.h>
#include <hip/hip_bf16.h>
#include <math.h>

typedef float  f32x4 __attribute__((ext_vector_type(4)));
typedef short  s16x8 __attribute__((ext_vector_type(8)));
typedef unsigned int u32x2 __attribute__((ext_vector_type(2)));
typedef unsigned int u32x4 __attribute__((ext_vector_type(4)));

constexpr int kNRays = 16384;
constexpr int kTableSize = 1 << 19;
constexpr int kOffDepth   = kNRays * 3;
constexpr int kOffAcc     = kOffDepth + kNRays;
constexpr int kOffWeights = kOffAcc + kNRays;

// Pre-staged A-fragment regions in d_ws (ushort offsets)
constexpr int kWg0 = 0;      // 32x64  KT=1 MT=4 -> 2048
constexpr int kWg1 = 2048;   // 64x64  KT=2 MT=4 -> 4096
constexpr int kWd  = 6144;   // 64x16  KT=2 MT=1 -> 1024 (dperm)
constexpr int kWc0 = 7168;   // 24x64  KT=1 MT=4 -> 2048
constexpr int kWc1 = 9216;   // 64x64  -> 4096
constexpr int kWc2 = 13312;  // 64x64  -> 4096
constexpr int kWch = 17408;  // 64x3   KT=2 MT=1 -> 1024
constexpr int kWsTotal = 18432;

__device__ __forceinline__ ushort f2bf(float x) {
    unsigned u = __float_as_uint(x);
    return (ushort)((u + 0x7FFFu + ((u >> 16) & 1u)) >> 16);
}
__device__ __forceinline__ unsigned pk2(float lo, float hi) {
    __hip_bfloat162 h = __float22bfloat162_rn(float2{lo, hi});
    return *reinterpret_cast<unsigned*>(&h);   // v_cvt_pk_bf16_f32
}
__device__ __forceinline__ float sel4(float v0, float v1, float v2, float v3, int s) {
    float a = (s & 1) ? v1 : v0;
    float b = (s & 1) ? v3 : v2;
    return (s & 2) ? b : a;
}
__device__ __forceinline__ float wave_sum(float v) {
#pragma unroll
    for (int off = 32; off > 0; off >>= 1) v += __shfl_xor(v, off, 64);
    return v;
}

// One-time weight staging: W (f32 [FIN][FOUT]) -> bf16 A-fragments in ws.
__global__ __launch_bounds__(256) void prep_weights(
    const float* __restrict__ Wg0, const float* __restrict__ Wg1,
    const float* __restrict__ Wd,  const float* __restrict__ Wc0,
    const float* __restrict__ Wc1, const float* __restrict__ Wc2,
    const float* __restrict__ Wch, ushort* __restrict__ ws)
{
    const int i = blockIdx.x * 256 + threadIdx.x;
    if (i >= kWsTotal) return;
    const float* W; int FIN, FOUT, KT, base; bool dperm = false;
    if (i < kWg1)      { W = Wg0; FIN = 32; FOUT = 64; KT = 1; base = kWg0; }
    else if (i < kWd)  { W = Wg1; FIN = 64; FOUT = 64; KT = 2; base = kWg1; }
    else if (i < kWc0) { W = Wd;  FIN = 64; FOUT = 16; KT = 2; base = kWd; dperm = true; }
    else if (i < kWc1) { W = Wc0; FIN = 24; FOUT = 64; KT = 1; base = kWc0; }
    else if (i < kWc2) { W = Wc1; FIN = 64; FOUT = 64; KT = 2; base = kWc1; }
    else if (i < kWch) { W = Wc2; FIN = 64; FOUT = 64; KT = 2; base = kWc2; }
    else               { W = Wch; FIN = 64; FOUT = 3;  KT = 2; base = kWch; }
    const int r = i - base;
    const int e = r & 7, l = (r >> 3) & 63, t = r >> 9;
    const int kt = t % KT, mt = t / KT;
    const int k = kt * 32 + ((l >> 4) << 3) + e;
    int j = mt * 16 + (l & 15);
    if (dperm) j = (j == 15) ? 0 : j + 1;   // geo[0] -> row 15, geo[1..15] -> rows 0..14
    float w = 0.0f;
    if (k < FIN && j < FOUT) w = W[k * FOUT + j];
    ws[i] = f2bf(w);
}

// Fused 64-out layer: B from X, A from ws, per-mt acc + immediate relu/pack/store.
// Low register pressure: B[KT][4] stays live; acc is 16 VGPRs at a time.
template<int KT, bool RELU>
__device__ __forceinline__ void layer64(ushort* Xw, const ushort* __restrict__ Aws,
                                        const float* __restrict__ bias,
                                        int c16, int g, int lane) {
    s16x8 B[KT][4];
#pragma unroll
    for (int kt = 0; kt < KT; ++kt)
#pragma unroll
        for (int nt = 0; nt < 4; ++nt) {
            const int col = nt * 16 + c16;
            B[kt][nt] = *(const s16x8*)&Xw[col * 64 + 8 * ((kt * 4 + g) ^ (c16 & 7))];
        }
#pragma unroll
    for (int mt = 0; mt < 4; ++mt) {
        const s16x8 A0 = *(const s16x8*)&Aws[((mt * KT + 0) * 64 + lane) * 8];
        s16x8 A1;
        if constexpr (KT == 2) A1 = *(const s16x8*)&Aws[((mt * KT + 1) * 64 + lane) * 8];
        const f32x4 b = *(const f32x4*)(bias + mt * 16 + g * 4);
        f32x4 acc[4];
#pragma unroll
        for (int nt = 0; nt < 4; ++nt) {
            acc[nt] = b;
            acc[nt] = __builtin_amdgcn_mfma_f32_16x16x32_bf16(A0, B[0][nt], acc[nt], 0, 0, 0);
            if constexpr (KT == 2)
                acc[nt] = __builtin_amdgcn_mfma_f32_16x16x32_bf16(A1, B[1][nt], acc[nt], 0, 0, 0);
        }
#pragma unroll
        for (int nt = 0; nt < 4; ++nt) {
            const int col = nt * 16 + c16;
            float x0 = acc[nt].x, x1 = acc[nt].y, x2 = acc[nt].z, x3 = acc[nt].w;
            if (RELU) {
                x0 = fmaxf(x0, 0.f); x1 = fmaxf(x1, 0.f);
                x2 = fmaxf(x2, 0.f); x3 = fmaxf(x3, 0.f);
            }
            const int a = col * 64 + 8 * ((2 * mt + (g >> 1)) ^ (c16 & 7)) + 4 * (g & 1);
            *(u32x2*)&Xw[a] = (u32x2){ pk2(x0, x1), pk2(x2, x3) };
        }
    }
}

// Small (16-col-out) layer: MT=1, returns acc tiles.
template<int KT>
__device__ __forceinline__ void layer16(const ushort* Xw, const ushort* __restrict__ Aws,
                                        int c16, int g, int lane, f32x4 acc[4]) {
    const s16x8 A0 = *(const s16x8*)&Aws[(0 * 64 + lane) * 8];
    s16x8 A1;
    if constexpr (KT == 2) A1 = *(const s16x8*)&Aws[(1 * 64 + lane) * 8];
#pragma unroll
    for (int nt = 0; nt < 4; ++nt) {
        const int col = nt * 16 + c16;
        const s16x8 B0 = *(const s16x8*)&Xw[col * 64 + 8 * ((0 * 4 + g) ^ (c16 & 7))];
        acc[nt] = __builtin_amdgcn_mfma_f32_16x16x32_bf16(A0, B0, acc[nt], 0, 0, 0);
        if constexpr (KT == 2) {
            const s16x8 B1 = *(const s16x8*)&Xw[col * 64 + 8 * ((1 * 4 + g) ^ (c16 & 7))];
            acc[nt] = __builtin_amdgcn_mfma_f32_16x16x32_bf16(A1, B1, acc[nt], 0, 0, 0);
        }
    }
}

__global__ __launch_bounds__(256, 4) void nerf_mfma_kernel(
    const float* __restrict__ rays_o, const float* __restrict__ rays_d,
    const float* __restrict__ tables, const ushort* __restrict__ ws,
    const float* __restrict__ bg0, const float* __restrict__ bg1,
    const float* __restrict__ bd,  const float* __restrict__ bc0,
    const float* __restrict__ bc1, const float* __restrict__ bc2,
    const float* __restrict__ bch, float* __restrict__ out)
{
    __shared__ __align__(16) ushort Xs[4 * 4096];
    const int tid  = threadIdx.x;
    const int wid  = tid >> 6;
    const int lane = tid & 63;
    const int c16  = lane & 15;
    const int g    = lane >> 4;
    const int ray  = blockIdx.x * 4 + wid;
    ushort* Xw = Xs + wid * 4096;

    const float ox = rays_o[ray * 3 + 0], oy = rays_o[ray * 3 + 1], oz = rays_o[ray * 3 + 2];
    const float dx = rays_d[ray * 3 + 0], dy = rays_d[ray * 3 + 1], dz = rays_d[ray * 3 + 2];

    const float step = 1.0f / 63.0f;
    const float z  = 0.1f + 1.4f * ((float)lane * step);
    const float zn = 0.1f + 1.4f * ((float)(lane + 1) * step);

    // ---- input-layer B fragments straight from the hash gather ----
    // lane (g,c16), tile nt: sample s = nt*16+c16, levels g*4+j
    s16x8 B0[4];
#pragma unroll
    for (int nt = 0; nt < 4; ++nt) {
        const int s = nt * 16 + c16;
        const float zs = 0.1f + 1.4f * ((float)s * step);
        const float px = ox + dx * zs, py = oy + dy * zs, pz = oz + dz * zs;
        u32x4 val;
#pragma unroll
        for (int j = 0; j < 4; ++j) {
            const int lv = g * 4 + j;
            const float res = (float)(32 << lv);
            const float rm1 = res - 1.0f;
            float sx = (px + 1.0f) * 0.5f * rm1; sx = fminf(fmaxf(sx, 0.f), rm1);
            float sy = (py + 1.0f) * 0.5f * rm1; sy = fminf(fmaxf(sy, 0.f), rm1);
            float sz = (pz + 1.0f) * 0.5f * rm1; sz = fminf(fmaxf(sz, 0.f), rm1);
            const float idxf = sx * res * res + sy * res + sz;
            const float szm1 = (lv == 0) ? 32767.f : (lv == 1) ? 262143.f : 524287.f;
            const int idx = (int)fminf(idxf, szm1);
            const float2 f2 = *reinterpret_cast<const float2*>(
                tables + ((size_t)lv * kTableSize + (size_t)idx) * 2);
            val[j] = pk2(f2.x, f2.y);
        }
        B0[nt] = *(const s16x8*)&val;
    }

    // ---- g0: 32 -> 64, relu (B direct from gather), per-mt fused store ----
#pragma unroll
    for (int mt = 0; mt < 4; ++mt) {
        const s16x8 A0 = *(const s16x8*)&ws[kWg0 + (mt * 64 + lane) * 8];
        const f32x4 b = *(const f32x4*)(bg0 + mt * 16 + g * 4);
        f32x4 acc[4];
#pragma unroll
        for (int nt = 0; nt < 4; ++nt) {
            acc[nt] = b;
            acc[nt] = __builtin_amdgcn_mfma_f32_16x16x32_bf16(A0, B0[nt], acc[nt], 0, 0, 0);
        }
#pragma unroll
        for (int nt = 0; nt < 4; ++nt) {
            const int col = nt * 16 + c16;
            const float x0 = fmaxf(acc[nt].x, 0.f), x1 = fmaxf(acc[nt].y, 0.f);
            const float x2 = fmaxf(acc[nt].z, 0.f), x3 = fmaxf(acc[nt].w, 0.f);
            const int a = col * 64 + 8 * ((2 * mt + (g >> 1)) ^ (c16 & 7)) + 4 * (g & 1);
            *(u32x2*)&Xw[a] = (u32x2){ pk2(x0, x1), pk2(x2, x3) };
        }
    }

    // ---- g1: 64 -> 64, relu ----
    layer64<2, true>(Xw, ws + kWg1, bg1, c16, g, lane);

    // ---- d: 64 -> 16 (cols rotated; row 15 = geo[0]) ----
    f32x4 accd[4];
    {
        const float db0 = bd[g * 4 + 1];
        const float db1 = bd[g * 4 + 2];
        const float db2 = bd[g * 4 + 3];
        const int i3 = (g == 3) ? 0 : g * 4 + 4;
        const float db3 = bd[i3];
        const f32x4 b = { db0, db1, db2, db3 };
#pragma unroll
        for (int nt = 0; nt < 4; ++nt) accd[nt] = b;
    }
    layer16<2>(Xw, ws + kWd, c16, g, lane, accd);
    const float lgit = sel4(__shfl(accd[0].w, 48 + c16, 64),
                            __shfl(accd[1].w, 48 + c16, 64),
                            __shfl(accd[2].w, 48 + c16, 64),
                            __shfl(accd[3].w, 48 + c16, 64), g);
    // store c_in rows 0..15 (row 15 junk, fixed below)
#pragma unroll
    for (int nt = 0; nt < 4; ++nt) {
        const int col = nt * 16 + c16;
        const int a = col * 64 + 8 * ((g >> 1) ^ (c16 & 7)) + 4 * (g & 1);
        *(u32x2*)&Xw[a] = (u32x2){ pk2(accd[nt].x, accd[nt].y), pk2(accd[nt].z, accd[nt].w) };
    }
    Xw[lane * 64 + 8 * (1 ^ (lane & 7)) + 7] = 0x3F00; // row 15 := bf16(0.5)
    {   // SH rows 16..23 (per-ray uniform)
        u32x4 w = { pk2(dx, dy), pk2(dz, dx * dy), pk2(dx * dz, dy * dz),
                    pk2(dx * dx - dy * dy, 3.f * dz * dz - 1.f) };
        *(u32x4*)&Xw[lane * 64 + 8 * (2 ^ (lane & 7))] = w;
    }

    // ---- color MLP ----
    layer64<1, true>(Xw, ws + kWc0, bc0, c16, g, lane);
    layer64<2, true>(Xw, ws + kWc1, bc1, c16, g, lane);
    layer64<2, true>(Xw, ws + kWc2, bc2, c16, g, lane);

    // ---- ch: 64 -> 3 ----
    f32x4 accc[4];
    {
        const float cb0 = bch[0], cb1 = bch[1], cb2 = bch[2];
        const f32x4 b = (g == 0) ? (f32x4){ cb0, cb1, cb2, 0.f } : (f32x4){ 0.f, 0.f, 0.f, 0.f };
#pragma unroll
        for (int nt = 0; nt < 4; ++nt) accc[nt] = b;
    }
    layer16<2>(Xw, ws + kWch, c16, g, lane, accc);
    const float lr = sel4(__shfl(accc[0].x, c16, 64), __shfl(accc[1].x, c16, 64),
                          __shfl(accc[2].x, c16, 64), __shfl(accc[3].x, c16, 64), g);
    const float lgr = sel4(__shfl(accc[0].y, c16, 64), __shfl(accc[1].y, c16, 64),
                           __shfl(accc[2].y, c16, 64), __shfl(accc[3].y, c16, 64), g);
    const float lb = sel4(__shfl(accc[0].z, c16, 64), __shfl(accc[1].z, c16, 64),
                          __shfl(accc[2].z, c16, 64), __shfl(accc[3].z, c16, 64), g);

    const float cr = 1.f / (1.f + expf(-lr));
    const float cg = 1.f / (1.f + expf(-lgr));
    const float cb = 1.f / (1.f + expf(-lb));
    const float gx = lgit - 1.0f;
    const float density = fmaxf(gx, 0.f) + log1pf(expf(-fabsf(gx)));

    // ---- volume rendering ----
    const float dnorm = sqrtf(dx * dx + dy * dy + dz * dz);
    float dist = (lane < 63) ? (zn - z) : 1e10f;
    dist *= dnorm;
    const float alpha = 1.0f - expf(-density * dist);
    float f = 1.0f - alpha + 1e-10f;
#pragma unroll
    for (int off = 1; off < 64; off <<= 1) {
        const float gg = __shfl_up(f, off, 64);
        if (lane >= off) f *= gg;
    }
    float T = __shfl_up(f, 1, 64);
    if (lane == 0) T = 1.0f;
    const float w = alpha * T;

    out[kOffWeights + ray * 64 + lane] = w;
    const float sr = wave_sum(w * cr);
    const float sg = wave_sum(w * cg);
    const float sb = wave_sum(w * cb);
    const float sd = wave_sum(w * z);
    const float sa = wave_sum(w);
    if (lane == 0) {
        out[ray * 3 + 0] = sr;
        out[ray * 3 + 1] = sg;
        out[ray * 3 + 2] = sb;
        out[kOffDepth + ray] = sd;
        out[kOffAcc + ray]   = sa;
    }
}

extern "C" void kernel_launch(void* const* d_in, const int* in_sizes, int n_in,
                              void* d_out, int out_size, void* d_ws, size_t ws_size,
                              hipStream_t stream) {
    const float* rays_o = (const float*)d_in[0];
    const float* rays_d = (const float*)d_in[1];
    const float* tables = (const float*)d_in[2];
    const float* Wg0 = (const float*)d_in[3];
    const float* bg0 = (const float*)d_in[4];
    const float* Wg1 = (const float*)d_in[5];
    const float* bg1 = (const float*)d_in[6];
    const float* Wd  = (const float*)d_in[7];
    const float* bd  = (const float*)d_in[8];
    const float* Wc0 = (const float*)d_in[9];
    const float* bc0 = (const float*)d_in[10];
    const float* Wc1 = (const float*)d_in[11];
    const float* bc1 = (const float*)d_in[12];
    const float* Wc2 = (const float*)d_in[13];
    const float* bc2 = (const float*)d_in[14];
    const float* Wch = (const float*)d_in[15];
    const float* bch = (const float*)d_in[16];
    float* out = (float*)d_out;
    ushort* wsp = (ushort*)d_ws;

    prep_weights<<<dim3((kWsTotal + 255) / 256), dim3(256), 0, stream>>>(
        Wg0, Wg1, Wd, Wc0, Wc1, Wc2, Wch, wsp);

    nerf_mfma_kernel<<<dim3(kNRays / 4), dim3(256), 0, stream>>>(
        rays_o, rays_d, tables, wsp,
        bg0, bg1, bd, bc0, bc1, bc2, bch, out);
}